// Round 9
// baseline (1289.255 us; speedup 1.0000x reference)
//
#include <hip/hip_runtime.h>

typedef __attribute__((ext_vector_type(4))) float f32x4;
typedef __attribute__((ext_vector_type(8))) __bf16 bf16x8;
typedef __attribute__((ext_vector_type(4))) float f32x4v;

#define BK 64
#define TOTALW 4096
static const size_t WTOT = 2752512ull;           // sum w^2

__device__ __forceinline__ bf16x8 cvt8(f32x4 a, f32x4 b) {
  bf16x8 r;
  r[0] = (__bf16)a.x; r[1] = (__bf16)a.y; r[2] = (__bf16)a.z; r[3] = (__bf16)a.w;
  r[4] = (__bf16)b.x; r[5] = (__bf16)b.y; r[6] = (__bf16)b.z; r[7] = (__bf16)b.w;
  return r;
}

// ---------------- pass 1: fp32 -> bf16 convert of W only (5.5 MB, ~10us) ----------------
struct WCArgs { const float* W[8]; ushort* ws; };

__global__ __launch_bounds__(256) void wconvert_kernel(WCArgs a) {
  const size_t e = ((size_t)blockIdx.x * 256 + threadIdx.x) << 3;
  if (e >= WTOT) return;
  int l = 0; size_t base = 0;
  if (e >= 16384)   { l = 1; base = 16384; }
  if (e >= 32768)   { l = 2; base = 32768; }
  if (e >= 180224)  { l = 3; base = 180224; }
  if (e >= 327680)  { l = 4; base = 327680; }
  if (e >= 737280)  { l = 5; base = 737280; }
  if (e >= 1146880) { l = 6; base = 1146880; }
  if (e >= 1949696) { l = 7; base = 1949696; }
  const float* w = a.W[0];
  if (l == 1) w = a.W[1]; if (l == 2) w = a.W[2]; if (l == 3) w = a.W[3];
  if (l == 4) w = a.W[4]; if (l == 5) w = a.W[5]; if (l == 6) w = a.W[6];
  if (l == 7) w = a.W[7];
  const float* src = w + (e - base);
  f32x4 v0 = *(const f32x4*)src;
  f32x4 v1 = *(const f32x4*)(src + 4);
  *(bf16x8*)(a.ws + e) = cvt8(v0, v1);
}

// ---------------- pass 2: fused GEMM: x read fp32 (reg-staged A, cvt on the fly), ----------------
// W read bf16 via global_load_lds. A-loads are issued one full K-step ahead and
// stay in flight across both barriers (counted vmcnt waits only B's 4 loads).
struct GArgs { const float* x; const ushort* Wb[8]; float* out; };

__device__ __forceinline__ void gl16(const ushort* g, ushort* l) {
  __builtin_amdgcn_global_load_lds(
      (const __attribute__((address_space(1))) void*)g,
      (__attribute__((address_space(3))) void*)l, 16, 0, 0);
}

__global__ __launch_bounds__(512, 4) void gemm_kernel(GArgs args) {
  __shared__ __align__(16) ushort As[128 * BK];   // 16 KB bf16 (written swizzled by ds_write)
  __shared__ __align__(16) ushort Bs[256 * BK];   // 32 KB bf16 (gl16 linear dest, source pre-XOR)

  const int tid = threadIdx.x;
  const int bid = blockIdx.x;
  // XCD-aware bijective swizzle: 5120 blocks, 640 per XCD (32 mt x 20 tiles)
  const int work = (bid & 7) * 640 + (bid >> 3);
  const int mt = work / 20;
  const int t  = 19 - (work - mt * 20);          // heavy-first

  // t -> (l, j): per-l 256-wide tile counts {1,1,2,2,3,3,4,4}; last tile of each l is 128 wide
  const int l = (t >= 1) + (t >= 2) + (t >= 4) + (t >= 6) + (t >= 9) + (t >= 12) + (t >= 16);
  const int p = l >> 1, q = l & 1;
  const int nirr = l | 1;                        // {1,1,3,3,5,5,7,7}
  const int cstart = 2 * p * p + q * nirr;
  const int w  = nirr << 7;                      // K for this block
  const int nk = nirr << 1;                      // K-steps (always even)
  const int sK = cstart << 7;
  const int tstart = (p + q) * (p + 1);
  const int j = t - tstart;
  const bool tail = (j == p);                    // last tile: 128 wide
  const int col  = sK + j * 256;
  const int noff = j * 256;
  const ushort* __restrict__ Wbl = args.Wb[l];

  // ---- B staging (gl16): linear LDS dest, source chunk pre-XORed (rule 21)
  const int trow = tid >> 3;                     // 0..63
  const int schunk = (tid & 7) ^ (trow & 7);
  const ushort* bSrc = Wbl + (size_t)(noff + trow) * w + schunk * 8;

  // ---- A staging (regs): thread covers rows {trow, trow+64}, 8 fp32 each at sk
  const int sk = (tid & 7) << 3;
  const float* __restrict__ aSrc = args.x + (size_t)(mt * 128 + trow) * TOTALW + sK + sk;
  // swizzled ds_write targets ((trow+64)&7 == trow&7)
  ushort* aDst0 = &As[((trow      ) * BK + sk) ^ ((trow & 7) << 3)];
  ushort* aDst1 = &As[((trow + 64) * BK + sk) ^ ((trow & 7) << 3)];

  const int lane = tid & 63;
  const int wid  = tid >> 6;
  const int fr = lane & 15;
  const int kq = lane >> 4;

#define ALOAD(n0, n1, n2, n3, kt)                                   \
  {                                                                 \
    const float* ap_ = aSrc + (kt) * 64;                            \
    n0 = *(const f32x4*)ap_;  n1 = *(const f32x4*)(ap_ + 4);        \
    const float* ap2_ = ap_ + (size_t)64 * TOTALW;                  \
    n2 = *(const f32x4*)ap2_; n3 = *(const f32x4*)(ap2_ + 4);       \
  }

  if (!tail) {
    // ---- 128x256 tile: wave grid 2x4, wave tile 64x64 ----
    const int wr = (wid >> 2) << 6;
    const int wc = (wid & 3) << 6;
    f32x4v acc[4][4] = {};
    f32x4 p0, p1, p2, p3, q0, q1, q2, q3;

    auto iter = [&](f32x4& c0, f32x4& c1, f32x4& c2, f32x4& c3,
                    f32x4& n0, f32x4& n1, f32x4& n2, f32x4& n3, int kt) {
#pragma unroll
      for (int r = 0; r < 4; ++r)
        gl16(bSrc + (size_t)(r * 64) * w + (size_t)kt * 64, &Bs[r * 4096 + tid * 8]);
      __builtin_amdgcn_sched_barrier(0);           // pin: B issued before A
      const bool pf = kt + 1 < nk;
      if (pf) ALOAD(n0, n1, n2, n3, kt + 1);
      __builtin_amdgcn_sched_barrier(0);           // pin: A issued before wait
      *(bf16x8*)aDst0 = cvt8(c0, c1);
      *(bf16x8*)aDst1 = cvt8(c2, c3);
      if (pf) asm volatile("s_waitcnt vmcnt(4) lgkmcnt(0)" ::: "memory");  // B landed; A(kt+1) in flight
      else    asm volatile("s_waitcnt vmcnt(0) lgkmcnt(0)" ::: "memory");
      __builtin_amdgcn_sched_barrier(0);
      __builtin_amdgcn_s_barrier();
#pragma unroll
      for (int kk = 0; kk < 2; ++kk) {
        const int kb = kk * 32 + kq * 8;
        bf16x8 afr[4], bfr[4];
#pragma unroll
        for (int i = 0; i < 4; ++i) {
          const int ra = wr + i * 16 + fr;
          afr[i] = *(const bf16x8*)&As[(ra * BK + kb) ^ ((fr & 7) << 3)];
          const int rb = wc + i * 16 + fr;
          bfr[i] = *(const bf16x8*)&Bs[(rb * BK + kb) ^ ((fr & 7) << 3)];
        }
#pragma unroll
        for (int mi = 0; mi < 4; ++mi)
#pragma unroll
          for (int ni = 0; ni < 4; ++ni)
            acc[mi][ni] = __builtin_amdgcn_mfma_f32_16x16x32_bf16(afr[mi], bfr[ni], acc[mi][ni], 0, 0, 0);
      }
      __builtin_amdgcn_s_barrier();                // readers done before next overwrite
    };

    ALOAD(p0, p1, p2, p3, 0);
    for (int kt = 0; kt < nk; kt += 2) {
      iter(p0, p1, p2, p3, q0, q1, q2, q3, kt);
      iter(q0, q1, q2, q3, p0, p1, p2, p3, kt + 1);
    }

    float* op = args.out + (size_t)(mt * 128 + wr + kq * 4) * TOTALW + col + wc + fr;
#pragma unroll
    for (int mi = 0; mi < 4; ++mi) {
#pragma unroll
      for (int ni = 0; ni < 4; ++ni) {
        float* pp = op + (size_t)(mi * 16) * TOTALW + ni * 16;
        pp[0 * TOTALW] = acc[mi][ni][0];
        pp[1 * TOTALW] = acc[mi][ni][1];
        pp[2 * TOTALW] = acc[mi][ni][2];
        pp[3 * TOTALW] = acc[mi][ni][3];
      }
    }
  } else {
    // ---- 128x128 tail tile: wave grid 4x2, wave tile 32x64 ----
    const int wr = (wid >> 1) << 5;
    const int wc = (wid & 1) << 6;
    f32x4v acc[2][4] = {};
    f32x4 p0, p1, p2, p3, q0, q1, q2, q3;

    auto iter = [&](f32x4& c0, f32x4& c1, f32x4& c2, f32x4& c3,
                    f32x4& n0, f32x4& n1, f32x4& n2, f32x4& n3, int kt) {
#pragma unroll
      for (int r = 0; r < 2; ++r)
        gl16(bSrc + (size_t)(r * 64) * w + (size_t)kt * 64, &Bs[r * 4096 + tid * 8]);
      __builtin_amdgcn_sched_barrier(0);
      const bool pf = kt + 1 < nk;
      if (pf) ALOAD(n0, n1, n2, n3, kt + 1);
      __builtin_amdgcn_sched_barrier(0);
      *(bf16x8*)aDst0 = cvt8(c0, c1);
      *(bf16x8*)aDst1 = cvt8(c2, c3);
      if (pf) asm volatile("s_waitcnt vmcnt(4) lgkmcnt(0)" ::: "memory");
      else    asm volatile("s_waitcnt vmcnt(0) lgkmcnt(0)" ::: "memory");
      __builtin_amdgcn_sched_barrier(0);
      __builtin_amdgcn_s_barrier();
#pragma unroll
      for (int kk = 0; kk < 2; ++kk) {
        const int kb = kk * 32 + kq * 8;
        bf16x8 afr[2], bfr[4];
#pragma unroll
        for (int i = 0; i < 2; ++i) {
          const int ra = wr + i * 16 + fr;
          afr[i] = *(const bf16x8*)&As[(ra * BK + kb) ^ ((fr & 7) << 3)];
        }
#pragma unroll
        for (int i = 0; i < 4; ++i) {
          const int rb = wc + i * 16 + fr;
          bfr[i] = *(const bf16x8*)&Bs[(rb * BK + kb) ^ ((fr & 7) << 3)];
        }
#pragma unroll
        for (int mi = 0; mi < 2; ++mi)
#pragma unroll
          for (int ni = 0; ni < 4; ++ni)
            acc[mi][ni] = __builtin_amdgcn_mfma_f32_16x16x32_bf16(afr[mi], bfr[ni], acc[mi][ni], 0, 0, 0);
      }
      __builtin_amdgcn_s_barrier();
    };

    ALOAD(p0, p1, p2, p3, 0);
    for (int kt = 0; kt < nk; kt += 2) {
      iter(p0, p1, p2, p3, q0, q1, q2, q3, kt);
      iter(q0, q1, q2, q3, p0, p1, p2, p3, kt + 1);
    }

    float* op = args.out + (size_t)(mt * 128 + wr + kq * 4) * TOTALW + col + wc + fr;
#pragma unroll
    for (int mi = 0; mi < 2; ++mi) {
#pragma unroll
      for (int ni = 0; ni < 4; ++ni) {
        float* pp = op + (size_t)(mi * 16) * TOTALW + ni * 16;
        pp[0 * TOTALW] = acc[mi][ni][0];
        pp[1 * TOTALW] = acc[mi][ni][1];
        pp[2 * TOTALW] = acc[mi][ni][2];
        pp[3 * TOTALW] = acc[mi][ni][3];
      }
    }
  }
#undef ALOAD
}

// ---------------- fallback (round-1 kernel, used only if ws too small) ----------------
struct FArgs { const float* x; const float* W[8]; float* out; };

__global__ __launch_bounds__(256, 2) void ielin_fb(FArgs args) {
  __shared__ __align__(16) ushort As[128 * BK];
  __shared__ __align__(16) ushort Bs[128 * BK];
  const int tid = threadIdx.x;
  const int bid = blockIdx.x;
  const int work = (bid & 7) * 1024 + (bid >> 3);
  const int mt = work >> 5;
  const int c  = work & 31;
  const int l = (c >= 1) + (c >= 2) + (c >= 5) + (c >= 8) + (c >= 13) + (c >= 18) + (c >= 25);
  const int pp = l >> 1, qq = l & 1;
  const int nirr = l | 1;
  const int cstart = 2 * pp * pp + qq * nirr;
  const int w  = nirr << 7;
  const int sK = cstart << 7;
  const int noff = (c - cstart) << 7;
  const float* __restrict__ Wl = args.W[l];
  const int srow = tid >> 3;
  const int sk   = (tid & 7) << 3;
  const float* ap = args.x + (size_t)(mt * 128 + srow) * TOTALW + sK + sk;
  const float* bp = Wl + (size_t)(noff + srow) * w + sk;
  const size_t aStep = (size_t)32 * TOTALW;
  const size_t bStep = (size_t)32 * w;
  const int lane = tid & 63;
  const int wid  = tid >> 6;
  const int wr = (wid >> 1) << 6;
  const int wc = (wid & 1) << 6;
  const int fr = lane & 15;
  const int kq = lane >> 4;
  f32x4v acc[4][4] = {};
  f32x4 av[4][2], bv[4][2];
  const int nk = w >> 6;
  {
    const float* a = ap; const float* b = bp;
#pragma unroll
    for (int i = 0; i < 4; ++i) {
      av[i][0] = *(const f32x4*)(a); av[i][1] = *(const f32x4*)(a + 4); a += aStep;
      bv[i][0] = *(const f32x4*)(b); bv[i][1] = *(const f32x4*)(b + 4); b += bStep;
    }
  }
  for (int kt = 0; kt < nk; ++kt) {
#pragma unroll
    for (int i = 0; i < 4; ++i) {
      const int row = srow + 32 * i;
      const int e = (row * BK + sk) ^ ((row & 7) << 3);
      *(bf16x8*)&As[e] = cvt8(av[i][0], av[i][1]);
      *(bf16x8*)&Bs[e] = cvt8(bv[i][0], bv[i][1]);
    }
    __syncthreads();
    if (kt + 1 < nk) {
      const float* a = ap + (kt + 1) * BK;
      const float* b = bp + (kt + 1) * BK;
#pragma unroll
      for (int i = 0; i < 4; ++i) {
        av[i][0] = *(const f32x4*)(a); av[i][1] = *(const f32x4*)(a + 4); a += aStep;
        bv[i][0] = *(const f32x4*)(b); bv[i][1] = *(const f32x4*)(b + 4); b += bStep;
      }
    }
#pragma unroll
    for (int kk = 0; kk < 2; ++kk) {
      const int kb = kk * 32 + kq * 8;
      bf16x8 afr[4], bfr[4];
#pragma unroll
      for (int i = 0; i < 4; ++i) {
        const int ra = wr + i * 16 + fr;
        afr[i] = *(const bf16x8*)&As[(ra * BK + kb) ^ ((fr & 7) << 3)];
        const int rb = wc + i * 16 + fr;
        bfr[i] = *(const bf16x8*)&Bs[(rb * BK + kb) ^ ((fr & 7) << 3)];
      }
#pragma unroll
      for (int mi = 0; mi < 4; ++mi)
#pragma unroll
        for (int ni = 0; ni < 4; ++ni)
          acc[mi][ni] = __builtin_amdgcn_mfma_f32_16x16x32_bf16(afr[mi], bfr[ni], acc[mi][ni], 0, 0, 0);
    }
    __syncthreads();
  }
  float* op = args.out + (size_t)(mt * 128 + wr + kq * 4) * TOTALW + (c << 7) + wc + fr;
#pragma unroll
  for (int mi = 0; mi < 4; ++mi) {
#pragma unroll
    for (int ni = 0; ni < 4; ++ni) {
      float* pp = op + (size_t)(mi * 16) * TOTALW + ni * 16;
      pp[0 * TOTALW] = acc[mi][ni][0];
      pp[1 * TOTALW] = acc[mi][ni][1];
      pp[2 * TOTALW] = acc[mi][ni][2];
      pp[3 * TOTALW] = acc[mi][ni][3];
    }
  }
}

extern "C" void kernel_launch(void* const* d_in, const int* in_sizes, int n_in,
                              void* d_out, int out_size, void* d_ws, size_t ws_size,
                              hipStream_t stream) {
  if (ws_size >= WTOT * 2) {
    WCArgs wa;
    for (int i = 0; i < 8; ++i) wa.W[i] = (const float*)d_in[1 + i];
    wa.ws = (ushort*)d_ws;
    wconvert_kernel<<<1344, 256, 0, stream>>>(wa);   // 1344*256*8 == WTOT

    GArgs ga;
    ga.x = (const float*)d_in[0];
    static const size_t cumW[8] = {0, 16384, 32768, 180224, 327680, 737280, 1146880, 1949696};
    for (int i = 0; i < 8; ++i) ga.Wb[i] = (const ushort*)d_ws + cumW[i];
    ga.out = (float*)d_out;
    gemm_kernel<<<5120, 512, 0, stream>>>(ga);
  } else {
    FArgs fa;
    fa.x = (const float*)d_in[0];
    for (int i = 0; i < 8; ++i) fa.W[i] = (const float*)d_in[1 + i];
    fa.out = (float*)d_out;
    ielin_fb<<<8192, 256, 0, stream>>>(fa);
  }
}

// Round 10
// 643.837 us; speedup vs baseline: 2.0025x; 2.0025x over previous
//
#include <hip/hip_runtime.h>

typedef __attribute__((ext_vector_type(4))) float f32x4;
typedef __attribute__((ext_vector_type(8))) __bf16 bf16x8;
typedef __attribute__((ext_vector_type(4))) float f32x4v;

#define TOTALW 4096
static const size_t NXE = 134217728ull;          // NROW*TOTALW
static const size_t WTOT = 2752512ull;           // sum w^2

__device__ __forceinline__ bf16x8 cvt8(f32x4 a, f32x4 b) {
  bf16x8 r;
  r[0] = (__bf16)a.x; r[1] = (__bf16)a.y; r[2] = (__bf16)a.z; r[3] = (__bf16)a.w;
  r[4] = (__bf16)b.x; r[5] = (__bf16)b.y; r[6] = (__bf16)b.z; r[7] = (__bf16)b.w;
  return r;
}

// ---------------- pass 1: fp32 -> bf16 convert of x and all W into ws ----------------
struct CArgs { const float* x; const float* W[8]; ushort* ws; };

__global__ __launch_bounds__(256) void convert_kernel(CArgs a) {
  const size_t tot8 = (NXE + WTOT) >> 3;
  const size_t stride = (size_t)gridDim.x * blockDim.x;
  for (size_t i = (size_t)blockIdx.x * blockDim.x + threadIdx.x; i < tot8; i += stride) {
    const size_t e = i << 3;
    const float* src;
    if (e < NXE) {
      src = a.x + e;
    } else {
      const size_t ew = e - NXE;
      int l = 0; size_t base = 0;
      if (ew >= 16384)   { l = 1; base = 16384; }
      if (ew >= 32768)   { l = 2; base = 32768; }
      if (ew >= 180224)  { l = 3; base = 180224; }
      if (ew >= 327680)  { l = 4; base = 327680; }
      if (ew >= 737280)  { l = 5; base = 737280; }
      if (ew >= 1146880) { l = 6; base = 1146880; }
      if (ew >= 1949696) { l = 7; base = 1949696; }
      const float* w = a.W[0];
      if (l == 1) w = a.W[1]; if (l == 2) w = a.W[2]; if (l == 3) w = a.W[3];
      if (l == 4) w = a.W[4]; if (l == 5) w = a.W[5]; if (l == 6) w = a.W[6];
      if (l == 7) w = a.W[7];
      src = w + (ew - base);
    }
    f32x4 v0 = *(const f32x4*)src;
    f32x4 v1 = *(const f32x4*)(src + 4);
    *(bf16x8*)(a.ws + e) = cvt8(v0, v1);
  }
}

// ---------------- pass 2: bf16 GEMM, 8-phase schedule, 3-slot LDS pipeline ----------------
// m201 template port: 512 thr / 8 waves, 1 block/CU (144KB LDS), counted vmcnt(6/4)
// at phases 4 and 8 only, staging spread 2 gl16 per phase, 5-7 phase prefetch lead.
struct GArgs { const ushort* xb; const ushort* Wb[8]; float* out; };

__device__ __forceinline__ void gl16(const ushort* g, ushort* l) {
  __builtin_amdgcn_global_load_lds(
      (const __attribute__((address_space(1))) void*)g,
      (__attribute__((address_space(3))) void*)l, 16, 0, 0);
}

#define BARRIER() { __builtin_amdgcn_sched_barrier(0); __builtin_amdgcn_s_barrier(); __builtin_amdgcn_sched_barrier(0); }
#define VMW(n) asm volatile("s_waitcnt vmcnt(" #n ")" ::: "memory")

__global__ __launch_bounds__(512, 2) void gemm_kernel(GArgs args) {
  // 3 K-tile slots: A slot = 128x64 bf16 (16KB), B slot = 256x64 bf16 (32KB) -> 144KB
  __shared__ __align__(16) ushort As[3 * 8192];
  __shared__ __align__(16) ushort Bs[3 * 16384];

  const int tid = threadIdx.x;
  const int bid = blockIdx.x;
  const int work = (bid & 7) * 640 + (bid >> 3);   // XCD-chunked, 640/XCD
  const int mt = work / 20;
  const int t  = 19 - (work - mt * 20);            // heavy-first

  const int l = (t >= 1) + (t >= 2) + (t >= 4) + (t >= 6) + (t >= 9) + (t >= 12) + (t >= 16);
  const int p = l >> 1, q = l & 1;
  const int nirr = l | 1;
  const int cstart = 2 * p * p + q * nirr;
  const int w  = nirr << 7;                        // K
  const int nk = nirr << 1;                        // K-tiles of 64 (2,6,10,14)
  const int sK = cstart << 7;
  const int tstart = (p + q) * (p + 1);
  const int j = t - tstart;
  const bool tail = (j == p);                      // 128-wide last tile (incl. all of l0/l1)
  const int col  = sK + j * 256;
  const ushort* __restrict__ Wbl = args.Wb[l];

  // staging addressing (r7-proven): linear LDS dest, source chunk pre-XORed (rule 21)
  const int trow = tid >> 3;
  const int schunk = (tid & 7) ^ (trow & 7);
  const ushort* aSrc = args.xb + (size_t)(mt * 128 + trow) * TOTALW + sK + schunk * 8;
  const ushort* bSrc = Wbl + (size_t)(j * 256 + trow) * w + schunk * 8;

  const int lane = tid & 63;
  const int wid  = tid >> 6;
  const int fr = lane & 15;
  const int kq = lane >> 4;

#define SHB(s, kt, r) gl16(bSrc + (size_t)((r) * 64) * w + (size_t)(kt) * 64, &Bs[(s) * 16384 + (r) * 4096 + tid * 8])
#define SHBT(s, kt, r) gl16(bSrc + (size_t)((r) * 64) * w + (size_t)(kt) * 64, &Bs[(s) * 8192 + (r) * 4096 + tid * 8])
#define SHA(s, kt, r) gl16(aSrc + (size_t)((r) * 64) * TOTALW + (size_t)(kt) * 64, &As[(s) * 8192 + (r) * 4096 + tid * 8])

  if (!tail) {
    // ---- 128x256 tile: 2x4 wave grid, wave tile 64x64, acc 4x4 frags ----
    const int wr = (wid >> 2) << 6;
    const int wc = (wid & 3) << 6;
    f32x4v acc[4][4] = {};
    const int iters = nk >> 1;                     // 3,5,7 (main is l>=2)

#define PHM(s, mh, nh) { \
  const ushort* Ab = &As[(s) * 8192]; \
  const ushort* Bb = &Bs[(s) * 16384]; \
  __builtin_amdgcn_s_setprio(1); \
  _Pragma("unroll") \
  for (int kk = 0; kk < 2; ++kk) { \
    const int kb = kk * 32 + kq * 8; \
    bf16x8 af0 = *(const bf16x8*)&Ab[((wr + (mh) * 32 +  0 + fr) * 64 + kb) ^ ((fr & 7) << 3)]; \
    bf16x8 af1 = *(const bf16x8*)&Ab[((wr + (mh) * 32 + 16 + fr) * 64 + kb) ^ ((fr & 7) << 3)]; \
    bf16x8 bf0 = *(const bf16x8*)&Bb[((wc + (nh) * 32 +  0 + fr) * 64 + kb) ^ ((fr & 7) << 3)]; \
    bf16x8 bf1 = *(const bf16x8*)&Bb[((wc + (nh) * 32 + 16 + fr) * 64 + kb) ^ ((fr & 7) << 3)]; \
    acc[(mh)*2+0][(nh)*2+0] = __builtin_amdgcn_mfma_f32_16x16x32_bf16(af0, bf0, acc[(mh)*2+0][(nh)*2+0], 0, 0, 0); \
    acc[(mh)*2+0][(nh)*2+1] = __builtin_amdgcn_mfma_f32_16x16x32_bf16(af0, bf1, acc[(mh)*2+0][(nh)*2+1], 0, 0, 0); \
    acc[(mh)*2+1][(nh)*2+0] = __builtin_amdgcn_mfma_f32_16x16x32_bf16(af1, bf0, acc[(mh)*2+1][(nh)*2+0], 0, 0, 0); \
    acc[(mh)*2+1][(nh)*2+1] = __builtin_amdgcn_mfma_f32_16x16x32_bf16(af1, bf1, acc[(mh)*2+1][(nh)*2+1], 0, 0, 0); \
  } \
  __builtin_amdgcn_s_setprio(0); }

    // prologue: stage K0 -> slot0, K1 -> slot1 (6 loads each)
    SHB(0, 0, 0); SHB(0, 0, 1); SHB(0, 0, 2); SHB(0, 0, 3); SHA(0, 0, 0); SHA(0, 0, 1);
    SHB(1, 1, 0); SHB(1, 1, 1); SHB(1, 1, 2); SHB(1, 1, 3); SHA(1, 1, 0); SHA(1, 1, 1);
    __builtin_amdgcn_sched_barrier(0);
    VMW(6); BARRIER();                              // K0 ready, K1 in flight

    int se = 0;
    for (int it = 0; it < iters; ++it) {
      const int so = (se + 1 == 3) ? 0 : se + 1;
      const int s2 = (so + 1 == 3) ? 0 : so + 1;
      const int k2 = 2 * it + 2, k3 = 2 * it + 3;
      const bool st2 = k2 < nk, st3 = k3 < nk, lastit = (it + 1 == iters);
      // ph1-4: compute K-even (slot se); stage K2 -> slot s2
      if (st2) { SHB(s2, k2, 0); SHB(s2, k2, 1); }
      PHM(se, 0, 0); BARRIER();
      if (st2) { SHB(s2, k2, 2); SHB(s2, k2, 3); }
      PHM(se, 0, 1); BARRIER();
      if (st2) { SHA(s2, k2, 0); SHA(s2, k2, 1); }
      PHM(se, 1, 0); BARRIER();
      PHM(se, 1, 1);
      __builtin_amdgcn_sched_barrier(0);
      if (st2) { VMW(6); } else { VMW(0); }         // K-odd ready
      BARRIER();
      // ph5-8: compute K-odd (slot so); stage K3 -> slot se (freed at ph4 barrier)
      if (st3) { SHB(se, k3, 0); SHB(se, k3, 1); }
      PHM(so, 0, 0); BARRIER();
      if (st3) { SHB(se, k3, 2); SHB(se, k3, 3); }
      PHM(so, 0, 1); BARRIER();
      if (st3) { SHA(se, k3, 0); SHA(se, k3, 1); }
      PHM(so, 1, 0); BARRIER();
      PHM(so, 1, 1);
      if (!lastit) {
        __builtin_amdgcn_sched_barrier(0);
        if (st3) { VMW(6); } else { VMW(0); }       // K2 ready for next iter
        BARRIER();
      }
      se = s2;
    }

    float* op = args.out + (size_t)(mt * 128 + wr + kq * 4) * TOTALW + col + wc + fr;
#pragma unroll
    for (int mi = 0; mi < 4; ++mi) {
#pragma unroll
      for (int ni = 0; ni < 4; ++ni) {
        float* pp = op + (size_t)(mi * 16) * TOTALW + ni * 16;
        pp[0 * TOTALW] = acc[mi][ni][0];
        pp[1 * TOTALW] = acc[mi][ni][1];
        pp[2 * TOTALW] = acc[mi][ni][2];
        pp[3 * TOTALW] = acc[mi][ni][3];
      }
    }
  } else {
    // ---- 128x128 tail tile: 2x4 wave grid, wave tile 64x32, acc 4x2 frags ----
    const int wr = (wid >> 2) << 6;
    const int wc = (wid & 3) << 5;
    f32x4v acc[4][2] = {};
    const int iters = nk >> 1;                     // 1,3,5,7

#define PHT(s, mh, nh) { \
  const ushort* Ab = &As[(s) * 8192]; \
  const ushort* Bb = &Bs[(s) * 8192]; \
  __builtin_amdgcn_s_setprio(1); \
  _Pragma("unroll") \
  for (int kk = 0; kk < 2; ++kk) { \
    const int kb = kk * 32 + kq * 8; \
    bf16x8 af0 = *(const bf16x8*)&Ab[((wr + (mh) * 32 +  0 + fr) * 64 + kb) ^ ((fr & 7) << 3)]; \
    bf16x8 af1 = *(const bf16x8*)&Ab[((wr + (mh) * 32 + 16 + fr) * 64 + kb) ^ ((fr & 7) << 3)]; \
    bf16x8 bf0 = *(const bf16x8*)&Bb[((wc + (nh) * 16 + fr) * 64 + kb) ^ ((fr & 7) << 3)]; \
    acc[(mh)*2+0][nh] = __builtin_amdgcn_mfma_f32_16x16x32_bf16(af0, bf0, acc[(mh)*2+0][nh], 0, 0, 0); \
    acc[(mh)*2+1][nh] = __builtin_amdgcn_mfma_f32_16x16x32_bf16(af1, bf0, acc[(mh)*2+1][nh], 0, 0, 0); \
  } \
  __builtin_amdgcn_s_setprio(0); }

    // prologue: K0 -> slot0, K1 -> slot1 (4 loads each)
    SHBT(0, 0, 0); SHBT(0, 0, 1); SHA(0, 0, 0); SHA(0, 0, 1);
    SHBT(1, 1, 0); SHBT(1, 1, 1); SHA(1, 1, 0); SHA(1, 1, 1);
    __builtin_amdgcn_sched_barrier(0);
    VMW(4); BARRIER();

    int se = 0;
    for (int it = 0; it < iters; ++it) {
      const int so = (se + 1 == 3) ? 0 : se + 1;
      const int s2 = (so + 1 == 3) ? 0 : so + 1;
      const int k2 = 2 * it + 2, k3 = 2 * it + 3;
      const bool st2 = k2 < nk, st3 = k3 < nk, lastit = (it + 1 == iters);
      if (st2) { SHBT(s2, k2, 0); SHBT(s2, k2, 1); }
      PHT(se, 0, 0); BARRIER();
      if (st2) { SHA(s2, k2, 0); SHA(s2, k2, 1); }
      PHT(se, 0, 1); BARRIER();
      PHT(se, 1, 0); BARRIER();
      PHT(se, 1, 1);
      __builtin_amdgcn_sched_barrier(0);
      if (st2) { VMW(4); } else { VMW(0); }
      BARRIER();
      if (st3) { SHBT(se, k3, 0); SHBT(se, k3, 1); }
      PHT(so, 0, 0); BARRIER();
      if (st3) { SHA(se, k3, 0); SHA(se, k3, 1); }
      PHT(so, 0, 1); BARRIER();
      PHT(so, 1, 0); BARRIER();
      PHT(so, 1, 1);
      if (!lastit) {
        __builtin_amdgcn_sched_barrier(0);
        if (st3) { VMW(4); } else { VMW(0); }
        BARRIER();
      }
      se = s2;
    }

    float* op = args.out + (size_t)(mt * 128 + wr + kq * 4) * TOTALW + col + wc + fr;
#pragma unroll
    for (int mi = 0; mi < 4; ++mi) {
#pragma unroll
      for (int ni = 0; ni < 2; ++ni) {
        float* pp = op + (size_t)(mi * 16) * TOTALW + ni * 16;
        pp[0 * TOTALW] = acc[mi][ni][0];
        pp[1 * TOTALW] = acc[mi][ni][1];
        pp[2 * TOTALW] = acc[mi][ni][2];
        pp[3 * TOTALW] = acc[mi][ni][3];
      }
    }
  }
#undef SHB
#undef SHBT
#undef SHA
#undef PHM
#undef PHT
}

// ---------------- fallback (round-1 kernel, used only if ws too small) ----------------
struct FArgs { const float* x; const float* W[8]; float* out; };

__global__ __launch_bounds__(256, 2) void ielin_fb(FArgs args) {
  __shared__ __align__(16) ushort Asf[128 * 64];
  __shared__ __align__(16) ushort Bsf[128 * 64];
  const int tid = threadIdx.x;
  const int bid = blockIdx.x;
  const int work = (bid & 7) * 1024 + (bid >> 3);
  const int mt = work >> 5;
  const int c  = work & 31;
  const int l = (c >= 1) + (c >= 2) + (c >= 5) + (c >= 8) + (c >= 13) + (c >= 18) + (c >= 25);
  const int pp = l >> 1, qq = l & 1;
  const int nirr = l | 1;
  const int cstart = 2 * pp * pp + qq * nirr;
  const int w  = nirr << 7;
  const int sK = cstart << 7;
  const int noff = (c - cstart) << 7;
  const float* __restrict__ Wl = args.W[l];
  const int srow = tid >> 3;
  const int sk   = (tid & 7) << 3;
  const float* ap = args.x + (size_t)(mt * 128 + srow) * TOTALW + sK + sk;
  const float* bp = Wl + (size_t)(noff + srow) * w + sk;
  const size_t aStep = (size_t)32 * TOTALW;
  const size_t bStep = (size_t)32 * w;
  const int lane = tid & 63;
  const int wid  = tid >> 6;
  const int wr = (wid >> 1) << 6;
  const int wc = (wid & 1) << 6;
  const int fr = lane & 15;
  const int kq = lane >> 4;
  f32x4v acc[4][4] = {};
  f32x4 av[4][2], bv[4][2];
  const int nk = w >> 6;
  {
    const float* a = ap; const float* b = bp;
#pragma unroll
    for (int i = 0; i < 4; ++i) {
      av[i][0] = *(const f32x4*)(a); av[i][1] = *(const f32x4*)(a + 4); a += aStep;
      bv[i][0] = *(const f32x4*)(b); bv[i][1] = *(const f32x4*)(b + 4); b += bStep;
    }
  }
  for (int kt = 0; kt < nk; ++kt) {
#pragma unroll
    for (int i = 0; i < 4; ++i) {
      const int row = srow + 32 * i;
      const int e = (row * 64 + sk) ^ ((row & 7) << 3);
      *(bf16x8*)&Asf[e] = cvt8(av[i][0], av[i][1]);
      *(bf16x8*)&Bsf[e] = cvt8(bv[i][0], bv[i][1]);
    }
    __syncthreads();
    if (kt + 1 < nk) {
      const float* a = ap + (kt + 1) * 64;
      const float* b = bp + (kt + 1) * 64;
#pragma unroll
      for (int i = 0; i < 4; ++i) {
        av[i][0] = *(const f32x4*)(a); av[i][1] = *(const f32x4*)(a + 4); a += aStep;
        bv[i][0] = *(const f32x4*)(b); bv[i][1] = *(const f32x4*)(b + 4); b += bStep;
      }
    }
#pragma unroll
    for (int kk = 0; kk < 2; ++kk) {
      const int kb = kk * 32 + kq * 8;
      bf16x8 afr[4], bfr[4];
#pragma unroll
      for (int i = 0; i < 4; ++i) {
        const int ra = wr + i * 16 + fr;
        afr[i] = *(const bf16x8*)&Asf[(ra * 64 + kb) ^ ((fr & 7) << 3)];
        const int rb = wc + i * 16 + fr;
        bfr[i] = *(const bf16x8*)&Bsf[(rb * 64 + kb) ^ ((fr & 7) << 3)];
      }
#pragma unroll
      for (int mi = 0; mi < 4; ++mi)
#pragma unroll
        for (int ni = 0; ni < 4; ++ni)
          acc[mi][ni] = __builtin_amdgcn_mfma_f32_16x16x32_bf16(afr[mi], bfr[ni], acc[mi][ni], 0, 0, 0);
    }
    __syncthreads();
  }
  float* op = args.out + (size_t)(mt * 128 + wr + kq * 4) * TOTALW + (c << 7) + wc + fr;
#pragma unroll
  for (int mi = 0; mi < 4; ++mi) {
#pragma unroll
    for (int ni = 0; ni < 4; ++ni) {
      float* pq = op + (size_t)(mi * 16) * TOTALW + ni * 16;
      pq[0 * TOTALW] = acc[mi][ni][0];
      pq[1 * TOTALW] = acc[mi][ni][1];
      pq[2 * TOTALW] = acc[mi][ni][2];
      pq[3 * TOTALW] = acc[mi][ni][3];
    }
  }
}

extern "C" void kernel_launch(void* const* d_in, const int* in_sizes, int n_in,
                              void* d_out, int out_size, void* d_ws, size_t ws_size,
                              hipStream_t stream) {
  const size_t need = (NXE + WTOT) * 2;
  if (ws_size >= need) {
    CArgs ca;
    ca.x = (const float*)d_in[0];
    for (int i = 0; i < 8; ++i) ca.W[i] = (const float*)d_in[1 + i];
    ca.ws = (ushort*)d_ws;
    convert_kernel<<<4096, 256, 0, stream>>>(ca);

    GArgs ga;
    ga.xb = (const ushort*)d_ws;
    static const size_t cumW[8] = {0, 16384, 32768, 180224, 327680, 737280, 1146880, 1949696};
    for (int i = 0; i < 8; ++i) ga.Wb[i] = (const ushort*)d_ws + NXE + cumW[i];
    ga.out = (float*)d_out;
    gemm_kernel<<<5120, 512, 0, stream>>>(ga);
  } else {
    FArgs fa;
    fa.x = (const float*)d_in[0];
    for (int i = 0; i < 8; ++i) fa.W[i] = (const float*)d_in[1 + i];
    fa.out = (float*)d_out;
    ielin_fb<<<8192, 256, 0, stream>>>(fa);
  }
}

// Round 13
// 500.370 us; speedup vs baseline: 2.5766x; 1.2867x over previous
//
#include <hip/hip_runtime.h>

typedef __attribute__((ext_vector_type(4))) float f32x4;
typedef __attribute__((ext_vector_type(8))) __bf16 bf16x8;
typedef __attribute__((ext_vector_type(4))) float f32x4v;

#define TOTALW 4096
static const size_t NXE = 134217728ull;          // NROW*TOTALW
static const size_t WTOT = 2752512ull;           // sum w^2

__device__ __forceinline__ bf16x8 cvt8(f32x4 a, f32x4 b) {
  bf16x8 r;
  r[0] = (__bf16)a.x; r[1] = (__bf16)a.y; r[2] = (__bf16)a.z; r[3] = (__bf16)a.w;
  r[4] = (__bf16)b.x; r[5] = (__bf16)b.y; r[6] = (__bf16)b.z; r[7] = (__bf16)b.w;
  return r;
}

// ---------------- pass 1: fp32 -> bf16 convert of x and all W into ws ----------------
struct CArgs { const float* x; const float* W[8]; ushort* ws; };

__global__ __launch_bounds__(256) void convert_kernel(CArgs a) {
  const size_t tot8 = (NXE + WTOT) >> 3;
  const size_t stride = (size_t)gridDim.x * blockDim.x;
  for (size_t i = (size_t)blockIdx.x * blockDim.x + threadIdx.x; i < tot8; i += stride) {
    const size_t e = i << 3;
    const float* src;
    if (e < NXE) {
      src = a.x + e;
    } else {
      const size_t ew = e - NXE;
      int l = 0; size_t base = 0;
      if (ew >= 16384)   { l = 1; base = 16384; }
      if (ew >= 32768)   { l = 2; base = 32768; }
      if (ew >= 180224)  { l = 3; base = 180224; }
      if (ew >= 327680)  { l = 4; base = 327680; }
      if (ew >= 737280)  { l = 5; base = 737280; }
      if (ew >= 1146880) { l = 6; base = 1146880; }
      if (ew >= 1949696) { l = 7; base = 1949696; }
      const float* w = a.W[0];
      if (l == 1) w = a.W[1]; if (l == 2) w = a.W[2]; if (l == 3) w = a.W[3];
      if (l == 4) w = a.W[4]; if (l == 5) w = a.W[5]; if (l == 6) w = a.W[6];
      if (l == 7) w = a.W[7];
      src = w + (ew - base);
    }
    f32x4 v0 = *(const f32x4*)src;
    f32x4 v1 = *(const f32x4*)(src + 4);
    *(bf16x8*)(a.ws + e) = cvt8(v0, v1);
  }
}

// ---------------- pass 2: bf16 GEMM, 256x256 tile, m97 structure ----------------
// r7-proven loop (gl16 staging, XOR swizzle, vmcnt(0)+syncthreads, implicit TLP)
// with BM 128->256: halves x panel re-read demand (838->420 MB). 512 thr, 8 waves
// of 128x64 wave-tiles (acc[8][4]); 64KB LDS -> 2 blocks/CU.
struct GArgs { const ushort* xb; const ushort* Wb[8]; float* out; };

__device__ __forceinline__ void gl16(const ushort* g, ushort* l) {
  __builtin_amdgcn_global_load_lds(
      (const __attribute__((address_space(1))) void*)g,
      (__attribute__((address_space(3))) void*)l, 16, 0, 0);
}

__global__ __launch_bounds__(512, 2) void gemm_kernel(GArgs args) {
  __shared__ __align__(16) ushort As[256 * 64];   // 32 KB
  __shared__ __align__(16) ushort Bs[256 * 64];   // 32 KB (tail uses first 16 KB)

  const int tid = threadIdx.x;
  const int bid = blockIdx.x;
  // XCD-chunked: 2560 blocks, 320/XCD; mt-major so same-mt tiles (sharing the
  // A-panel) are temporally adjacent on one XCD.
  const int work = (bid & 7) * 320 + (bid >> 3);
  const int mt = work / 20;                        // 0..127 (rows of 256)
  const int t  = 19 - (work - mt * 20);            // heavy-first

  const int l = (t >= 1) + (t >= 2) + (t >= 4) + (t >= 6) + (t >= 9) + (t >= 12) + (t >= 16);
  const int p = l >> 1, q = l & 1;
  const int nirr = l | 1;                          // {1,1,3,3,5,5,7,7}
  const int cstart = 2 * p * p + q * nirr;
  const int w  = nirr << 7;                        // K
  const int nk = nirr << 1;                        // K-tiles of 64
  const int sK = cstart << 7;
  const int tstart = (p + q) * (p + 1);
  const int j = t - tstart;
  const bool tail = (j == p);                      // last tile 128 wide
  const int col  = sK + j * 256;
  const ushort* __restrict__ Wbl = args.Wb[l];

  // staging: linear LDS dest (rule 21), source k-chunk pre-XORed by row
  const int trow = tid >> 3;                       // 0..63
  const int schunk = (tid & 7) ^ (trow & 7);
  const ushort* aSrc = args.xb + (size_t)(mt * 256 + trow) * TOTALW + sK + schunk * 8;
  const ushort* bSrc = Wbl + (size_t)(j * 256 + trow) * w + schunk * 8;

  const int lane = tid & 63;
  const int wid  = tid >> 6;
  const int fr = lane & 15;
  const int kq = lane >> 4;

#define SHA(kt, r) gl16(aSrc + (size_t)((r) * 64) * TOTALW + (size_t)(kt) * 64, &As[(r) * 4096 + tid * 8])
#define SHB(kt, r) gl16(bSrc + (size_t)((r) * 64) * w + (size_t)(kt) * 64, &Bs[(r) * 4096 + tid * 8])

  const int wr = (wid >> 2) << 7;                  // 0 or 128
  if (!tail) {
    // ---- 256x256 tile: 2x4 wave grid, wave tile 128x64 ----
    const int wc = (wid & 3) << 6;
    f32x4v acc[8][4] = {};

    for (int kt = 0; kt < nk; ++kt) {
#pragma unroll
      for (int r = 0; r < 4; ++r) SHA(kt, r);
#pragma unroll
      for (int r = 0; r < 4; ++r) SHB(kt, r);
      asm volatile("s_waitcnt vmcnt(0)" ::: "memory");
      __syncthreads();

#pragma unroll
      for (int kk = 0; kk < 2; ++kk) {
        const int kb = kk * 32 + kq * 8;
        bf16x8 afr[8], bfr[4];
#pragma unroll
        for (int i = 0; i < 8; ++i) {
          const int ra = wr + i * 16 + fr;          // ra&7 == fr&7
          afr[i] = *(const bf16x8*)&As[(ra * 64 + kb) ^ ((fr & 7) << 3)];
        }
#pragma unroll
        for (int i = 0; i < 4; ++i) {
          const int rb = wc + i * 16 + fr;
          bfr[i] = *(const bf16x8*)&Bs[(rb * 64 + kb) ^ ((fr & 7) << 3)];
        }
#pragma unroll
        for (int mi = 0; mi < 8; ++mi)
#pragma unroll
          for (int ni = 0; ni < 4; ++ni)
            acc[mi][ni] = __builtin_amdgcn_mfma_f32_16x16x32_bf16(afr[mi], bfr[ni], acc[mi][ni], 0, 0, 0);
      }
      if (kt + 1 < nk) __syncthreads();
    }

    float* op = args.out + (size_t)(mt * 256 + wr + kq * 4) * TOTALW + col + wc + fr;
#pragma unroll
    for (int mi = 0; mi < 8; ++mi) {
#pragma unroll
      for (int ni = 0; ni < 4; ++ni) {
        float* pp = op + (size_t)(mi * 16) * TOTALW + ni * 16;
        pp[0 * TOTALW] = acc[mi][ni][0];
        pp[1 * TOTALW] = acc[mi][ni][1];
        pp[2 * TOTALW] = acc[mi][ni][2];
        pp[3 * TOTALW] = acc[mi][ni][3];
      }
    }
  } else {
    // ---- 256x128 tail tile: 2x4 wave grid, wave tile 128x32 ----
    const int wc = (wid & 3) << 5;
    f32x4v acc[8][2] = {};

    for (int kt = 0; kt < nk; ++kt) {
#pragma unroll
      for (int r = 0; r < 4; ++r) SHA(kt, r);
#pragma unroll
      for (int r = 0; r < 2; ++r) SHB(kt, r);
      asm volatile("s_waitcnt vmcnt(0)" ::: "memory");
      __syncthreads();

#pragma unroll
      for (int kk = 0; kk < 2; ++kk) {
        const int kb = kk * 32 + kq * 8;
        bf16x8 afr[8], bfr[2];
#pragma unroll
        for (int i = 0; i < 8; ++i) {
          const int ra = wr + i * 16 + fr;
          afr[i] = *(const bf16x8*)&As[(ra * 64 + kb) ^ ((fr & 7) << 3)];
        }
#pragma unroll
        for (int i = 0; i < 2; ++i) {
          const int rb = wc + i * 16 + fr;
          bfr[i] = *(const bf16x8*)&Bs[(rb * 64 + kb) ^ ((fr & 7) << 3)];
        }
#pragma unroll
        for (int mi = 0; mi < 8; ++mi)
#pragma unroll
          for (int ni = 0; ni < 2; ++ni)
            acc[mi][ni] = __builtin_amdgcn_mfma_f32_16x16x32_bf16(afr[mi], bfr[ni], acc[mi][ni], 0, 0, 0);
      }
      if (kt + 1 < nk) __syncthreads();
    }

    float* op = args.out + (size_t)(mt * 256 + wr + kq * 4) * TOTALW + col + wc + fr;
#pragma unroll
    for (int mi = 0; mi < 8; ++mi) {
#pragma unroll
      for (int ni = 0; ni < 2; ++ni) {
        float* pp = op + (size_t)(mi * 16) * TOTALW + ni * 16;
        pp[0 * TOTALW] = acc[mi][ni][0];
        pp[1 * TOTALW] = acc[mi][ni][1];
        pp[2 * TOTALW] = acc[mi][ni][2];
        pp[3 * TOTALW] = acc[mi][ni][3];
      }
    }
  }
#undef SHA
#undef SHB
}

// ---------------- fallback (round-1 kernel, used only if ws too small) ----------------
struct FArgs { const float* x; const float* W[8]; float* out; };

__global__ __launch_bounds__(256, 2) void ielin_fb(FArgs args) {
  __shared__ __align__(16) ushort Asf[128 * 64];
  __shared__ __align__(16) ushort Bsf[128 * 64];
  const int tid = threadIdx.x;
  const int bid = blockIdx.x;
  const int work = (bid & 7) * 1024 + (bid >> 3);
  const int mt = work >> 5;
  const int c  = work & 31;
  const int l = (c >= 1) + (c >= 2) + (c >= 5) + (c >= 8) + (c >= 13) + (c >= 18) + (c >= 25);
  const int pp = l >> 1, qq = l & 1;
  const int nirr = l | 1;
  const int cstart = 2 * pp * pp + qq * nirr;
  const int w  = nirr << 7;
  const int sK = cstart << 7;
  const int noff = (c - cstart) << 7;
  const float* __restrict__ Wl = args.W[l];
  const int srow = tid >> 3;
  const int sk   = (tid & 7) << 3;
  const float* ap = args.x + (size_t)(mt * 128 + srow) * TOTALW + sK + sk;
  const float* bp = Wl + (size_t)(noff + srow) * w + sk;
  const size_t aStep = (size_t)32 * TOTALW;
  const size_t bStep = (size_t)32 * w;
  const int lane = tid & 63;
  const int wid  = tid >> 6;
  const int wr = (wid >> 1) << 6;
  const int wc = (wid & 1) << 6;
  const int fr = lane & 15;
  const int kq = lane >> 4;
  f32x4v acc[4][4] = {};
  f32x4 av[4][2], bv[4][2];
  const int nk = w >> 6;
  {
    const float* a = ap; const float* b = bp;
#pragma unroll
    for (int i = 0; i < 4; ++i) {
      av[i][0] = *(const f32x4*)(a); av[i][1] = *(const f32x4*)(a + 4); a += aStep;
      bv[i][0] = *(const f32x4*)(b); bv[i][1] = *(const f32x4*)(b + 4); b += bStep;
    }
  }
  for (int kt = 0; kt < nk; ++kt) {
#pragma unroll
    for (int i = 0; i < 4; ++i) {
      const int row = srow + 32 * i;
      const int e = (row * 64 + sk) ^ ((row & 7) << 3);
      *(bf16x8*)&Asf[e] = cvt8(av[i][0], av[i][1]);
      *(bf16x8*)&Bsf[e] = cvt8(bv[i][0], bv[i][1]);
    }
    __syncthreads();
    if (kt + 1 < nk) {
      const float* a = ap + (kt + 1) * 64;
      const float* b = bp + (kt + 1) * 64;
#pragma unroll
      for (int i = 0; i < 4; ++i) {
        av[i][0] = *(const f32x4*)(a); av[i][1] = *(const f32x4*)(a + 4); a += aStep;
        bv[i][0] = *(const f32x4*)(b); bv[i][1] = *(const f32x4*)(b + 4); b += bStep;
      }
    }
#pragma unroll
    for (int kk = 0; kk < 2; ++kk) {
      const int kb = kk * 32 + kq * 8;
      bf16x8 afr[4], bfr[4];
#pragma unroll
      for (int i = 0; i < 4; ++i) {
        const int ra = wr + i * 16 + fr;
        afr[i] = *(const bf16x8*)&Asf[(ra * 64 + kb) ^ ((fr & 7) << 3)];
        const int rb = wc + i * 16 + fr;
        bfr[i] = *(const bf16x8*)&Bsf[(rb * 64 + kb) ^ ((fr & 7) << 3)];
      }
#pragma unroll
      for (int mi = 0; mi < 4; ++mi)
#pragma unroll
        for (int ni = 0; ni < 4; ++ni)
          acc[mi][ni] = __builtin_amdgcn_mfma_f32_16x16x32_bf16(afr[mi], bfr[ni], acc[mi][ni], 0, 0, 0);
    }
    __syncthreads();
  }
  float* op = args.out + (size_t)(mt * 128 + wr + kq * 4) * TOTALW + (c << 7) + wc + fr;
#pragma unroll
  for (int mi = 0; mi < 4; ++mi) {
#pragma unroll
    for (int ni = 0; ni < 4; ++ni) {
      float* pq = op + (size_t)(mi * 16) * TOTALW + ni * 16;
      pq[0 * TOTALW] = acc[mi][ni][0];
      pq[1 * TOTALW] = acc[mi][ni][1];
      pq[2 * TOTALW] = acc[mi][ni][2];
      pq[3 * TOTALW] = acc[mi][ni][3];
    }
  }
}

extern "C" void kernel_launch(void* const* d_in, const int* in_sizes, int n_in,
                              void* d_out, int out_size, void* d_ws, size_t ws_size,
                              hipStream_t stream) {
  const size_t need = (NXE + WTOT) * 2;
  if (ws_size >= need) {
    CArgs ca;
    ca.x = (const float*)d_in[0];
    for (int i = 0; i < 8; ++i) ca.W[i] = (const float*)d_in[1 + i];
    ca.ws = (ushort*)d_ws;
    convert_kernel<<<8192, 256, 0, stream>>>(ca);

    GArgs ga;
    ga.xb = (const ushort*)d_ws;
    static const size_t cumW[8] = {0, 16384, 32768, 180224, 327680, 737280, 1146880, 1949696};
    for (int i = 0; i < 8; ++i) ga.Wb[i] = (const ushort*)d_ws + NXE + cumW[i];
    ga.out = (float*)d_out;
    gemm_kernel<<<2560, 512, 0, stream>>>(ga);
  } else {
    FArgs fa;
    fa.x = (const float*)d_in[0];
    for (int i = 0; i < 8; ++i) fa.W[i] = (const float*)d_in[1 + i];
    fa.out = (float*)d_out;
    ielin_fb<<<8192, 256, 0, stream>>>(fa);
  }
}

// Round 14
// 371.689 us; speedup vs baseline: 3.4686x; 1.3462x over previous
//
#include <hip/hip_runtime.h>

typedef __attribute__((ext_vector_type(4))) float f32x4;
typedef __attribute__((ext_vector_type(8))) __bf16 bf16x8;
typedef __attribute__((ext_vector_type(4))) float f32x4v;

#define TOTALW 4096
static const size_t WTOT = 2752512ull;           // sum w^2

__device__ __forceinline__ bf16x8 cvt8(f32x4 a, f32x4 b) {
  bf16x8 r;
  r[0] = (__bf16)a.x; r[1] = (__bf16)a.y; r[2] = (__bf16)a.z; r[3] = (__bf16)a.w;
  r[4] = (__bf16)b.x; r[5] = (__bf16)b.y; r[6] = (__bf16)b.z; r[7] = (__bf16)b.w;
  return r;
}

// ---------------- pass 1: fp32 -> bf16 convert of W only (5.5 MB, ~10us) ----------------
struct WCArgs { const float* W[8]; ushort* ws; };

__global__ __launch_bounds__(256) void wconvert_kernel(WCArgs a) {
  const size_t e = ((size_t)blockIdx.x * 256 + threadIdx.x) << 3;
  if (e >= WTOT) return;
  int l = 0; size_t base = 0;
  if (e >= 16384)   { l = 1; base = 16384; }
  if (e >= 32768)   { l = 2; base = 32768; }
  if (e >= 180224)  { l = 3; base = 180224; }
  if (e >= 327680)  { l = 4; base = 327680; }
  if (e >= 737280)  { l = 5; base = 737280; }
  if (e >= 1146880) { l = 6; base = 1146880; }
  if (e >= 1949696) { l = 7; base = 1949696; }
  const float* w = a.W[0];
  if (l == 1) w = a.W[1]; if (l == 2) w = a.W[2]; if (l == 3) w = a.W[3];
  if (l == 4) w = a.W[4]; if (l == 5) w = a.W[5]; if (l == 6) w = a.W[6];
  if (l == 7) w = a.W[7];
  const float* src = w + (e - base);
  f32x4 v0 = *(const f32x4*)src;
  f32x4 v1 = *(const f32x4*)(src + 4);
  *(bf16x8*)(a.ws + e) = cvt8(v0, v1);
}

// ---------------- pass 2: fused GEMM (r7 structure; A read fp32 from x) ----------------
// r7-proven shell: BM=128, BN=256(+128 tail), BK=64, 512 thr, 48KB LDS -> 3 blocks/CU,
// XOR-swizzled LDS, vmcnt+syncthreads loop, implicit multi-block TLP.
// Change vs r7: A staged from x as fp32 (4x f32x4 -> cvt8 -> 2 swizzled ds_write_b128,
// r1-proven, named transients only — no lambdas, no cross-iter reg state / rule #20).
// A-loads issue FIRST, B gl16 second; vmcnt(4) waits A only so A/B latencies overlap.
// This deletes the x fp32->bf16 convert round-trip (~768 MB, ~125 us) entirely.
struct GArgs { const float* x; const ushort* Wb[8]; float* out; };

__device__ __forceinline__ void gl16(const ushort* g, ushort* l) {
  __builtin_amdgcn_global_load_lds(
      (const __attribute__((address_space(1))) void*)g,
      (__attribute__((address_space(3))) void*)l, 16, 0, 0);
}

__global__ __launch_bounds__(512, 2) void gemm_kernel(GArgs args) {
  __shared__ __align__(16) ushort As[128 * 64];   // 16 KB bf16 (ds_write, XOR-swizzled dest)
  __shared__ __align__(16) ushort Bs[256 * 64];   // 32 KB bf16 (gl16 linear dest, src pre-XOR)

  const int tid = threadIdx.x;
  const int bid = blockIdx.x;
  // XCD-chunked: 5120 blocks, 640/XCD, mt-major heavy-first (r7-proven)
  const int work = (bid & 7) * 640 + (bid >> 3);
  const int mt = work / 20;
  const int t  = 19 - (work - mt * 20);

  const int l = (t >= 1) + (t >= 2) + (t >= 4) + (t >= 6) + (t >= 9) + (t >= 12) + (t >= 16);
  const int p = l >> 1, q = l & 1;
  const int nirr = l | 1;                          // {1,1,3,3,5,5,7,7}
  const int cstart = 2 * p * p + q * nirr;
  const int w  = nirr << 7;                        // K
  const int nk = nirr << 1;                        // K-tiles of 64
  const int sK = cstart << 7;
  const int tstart = (p + q) * (p + 1);
  const int j = t - tstart;
  const bool tail = (j == p);                      // last tile 128 wide
  const int col  = sK + j * 256;
  const ushort* __restrict__ Wbl = args.Wb[l];

  // ---- B staging (gl16, r7-exact): linear LDS dest, source chunk pre-XORed (rule 21)
  const int trow = tid >> 3;                       // 0..63
  const int schunk = (tid & 7) ^ (trow & 7);
  const ushort* bSrc = Wbl + (size_t)(j * 256 + trow) * w + schunk * 8;

  // ---- A staging (fp32 regs -> cvt -> swizzled ds_write, r1-proven pattern)
  const int arow = tid >> 3;                       // 0..63; thread covers rows {arow, arow+64}
  const int ask  = (tid & 7) << 3;                 // k-offset 0..56
  const float* __restrict__ aSrc0 = args.x + (size_t)(mt * 128 + arow) * TOTALW + sK + ask;
  const float* __restrict__ aSrc1 = aSrc0 + (size_t)64 * TOTALW;
  ushort* aDst0 = &As[((arow     ) * 64 + ask) ^ ((arow & 7) << 3)];
  ushort* aDst1 = &As[((arow + 64) * 64 + ask) ^ ((arow & 7) << 3)];   // (arow+64)&7 == arow&7

  const int lane = tid & 63;
  const int wid  = tid >> 6;
  const int fr = lane & 15;
  const int kq = lane >> 4;

#define SHB(kt, r) gl16(bSrc + (size_t)((r) * 64) * w + (size_t)(kt) * 64, &Bs[(r) * 4096 + tid * 8])

  if (!tail) {
    // ---- 128x256 tile: 2x4 wave grid, wave tile 64x64 (r7-exact compute) ----
    const int wr = (wid >> 2) << 6;
    const int wc = (wid & 3) << 6;
    f32x4v acc[4][4] = {};

    for (int kt = 0; kt < nk; ++kt) {
      // A fp32 loads first (oldest in vmcnt queue)
      f32x4 a0 = *(const f32x4*)(aSrc0 + kt * 64);
      f32x4 a1 = *(const f32x4*)(aSrc0 + kt * 64 + 4);
      f32x4 a2 = *(const f32x4*)(aSrc1 + kt * 64);
      f32x4 a3 = *(const f32x4*)(aSrc1 + kt * 64 + 4);
      __builtin_amdgcn_sched_barrier(0);
      SHB(kt, 0); SHB(kt, 1); SHB(kt, 2); SHB(kt, 3);
      __builtin_amdgcn_sched_barrier(0);
      // wait A only (4 B-gl16 still in flight), convert+write to LDS
      asm volatile("s_waitcnt vmcnt(4)" ::: "memory");
      *(bf16x8*)aDst0 = cvt8(a0, a1);
      *(bf16x8*)aDst1 = cvt8(a2, a3);
      __builtin_amdgcn_sched_barrier(0);
      asm volatile("s_waitcnt vmcnt(0) lgkmcnt(0)" ::: "memory");
      __syncthreads();

#pragma unroll
      for (int kk = 0; kk < 2; ++kk) {
        const int kb = kk * 32 + kq * 8;
        bf16x8 afr[4], bfr[4];
#pragma unroll
        for (int i = 0; i < 4; ++i) {
          const int ra = wr + i * 16 + fr;          // ra&7 == fr&7
          afr[i] = *(const bf16x8*)&As[(ra * 64 + kb) ^ ((fr & 7) << 3)];
          const int rb = wc + i * 16 + fr;
          bfr[i] = *(const bf16x8*)&Bs[(rb * 64 + kb) ^ ((fr & 7) << 3)];
        }
#pragma unroll
        for (int mi = 0; mi < 4; ++mi)
#pragma unroll
          for (int ni = 0; ni < 4; ++ni)
            acc[mi][ni] = __builtin_amdgcn_mfma_f32_16x16x32_bf16(afr[mi], bfr[ni], acc[mi][ni], 0, 0, 0);
      }
      if (kt + 1 < nk) __syncthreads();
    }

    float* op = args.out + (size_t)(mt * 128 + wr + kq * 4) * TOTALW + col + wc + fr;
#pragma unroll
    for (int mi = 0; mi < 4; ++mi) {
#pragma unroll
      for (int ni = 0; ni < 4; ++ni) {
        float* pp = op + (size_t)(mi * 16) * TOTALW + ni * 16;
        pp[0 * TOTALW] = acc[mi][ni][0];
        pp[1 * TOTALW] = acc[mi][ni][1];
        pp[2 * TOTALW] = acc[mi][ni][2];
        pp[3 * TOTALW] = acc[mi][ni][3];
      }
    }
  } else {
    // ---- 128x128 tail tile: 4x2 wave grid, wave tile 32x64 (r7-exact) ----
    const int wr = (wid >> 1) << 5;
    const int wc = (wid & 1) << 6;
    f32x4v acc[2][4] = {};

    for (int kt = 0; kt < nk; ++kt) {
      f32x4 a0 = *(const f32x4*)(aSrc0 + kt * 64);
      f32x4 a1 = *(const f32x4*)(aSrc0 + kt * 64 + 4);
      f32x4 a2 = *(const f32x4*)(aSrc1 + kt * 64);
      f32x4 a3 = *(const f32x4*)(aSrc1 + kt * 64 + 4);
      __builtin_amdgcn_sched_barrier(0);
      SHB(kt, 0); SHB(kt, 1);
      __builtin_amdgcn_sched_barrier(0);
      asm volatile("s_waitcnt vmcnt(2)" ::: "memory");   // A done, 2 B-gl16 in flight
      *(bf16x8*)aDst0 = cvt8(a0, a1);
      *(bf16x8*)aDst1 = cvt8(a2, a3);
      __builtin_amdgcn_sched_barrier(0);
      asm volatile("s_waitcnt vmcnt(0) lgkmcnt(0)" ::: "memory");
      __syncthreads();

#pragma unroll
      for (int kk = 0; kk < 2; ++kk) {
        const int kb = kk * 32 + kq * 8;
        bf16x8 afr[2], bfr[4];
#pragma unroll
        for (int i = 0; i < 2; ++i) {
          const int ra = wr + i * 16 + fr;
          afr[i] = *(const bf16x8*)&As[(ra * 64 + kb) ^ ((fr & 7) << 3)];
        }
#pragma unroll
        for (int i = 0; i < 4; ++i) {
          const int rb = wc + i * 16 + fr;
          bfr[i] = *(const bf16x8*)&Bs[(rb * 64 + kb) ^ ((fr & 7) << 3)];
        }
#pragma unroll
        for (int mi = 0; mi < 2; ++mi)
#pragma unroll
          for (int ni = 0; ni < 4; ++ni)
            acc[mi][ni] = __builtin_amdgcn_mfma_f32_16x16x32_bf16(afr[mi], bfr[ni], acc[mi][ni], 0, 0, 0);
      }
      if (kt + 1 < nk) __syncthreads();
    }

    float* op = args.out + (size_t)(mt * 128 + wr + kq * 4) * TOTALW + col + wc + fr;
#pragma unroll
    for (int mi = 0; mi < 2; ++mi) {
#pragma unroll
      for (int ni = 0; ni < 4; ++ni) {
        float* pp = op + (size_t)(mi * 16) * TOTALW + ni * 16;
        pp[0 * TOTALW] = acc[mi][ni][0];
        pp[1 * TOTALW] = acc[mi][ni][1];
        pp[2 * TOTALW] = acc[mi][ni][2];
        pp[3 * TOTALW] = acc[mi][ni][3];
      }
    }
  }
#undef SHB
}

// ---------------- fallback (round-1 kernel, used only if ws too small) ----------------
struct FArgs { const float* x; const float* W[8]; float* out; };

__global__ __launch_bounds__(256, 2) void ielin_fb(FArgs args) {
  __shared__ __align__(16) ushort Asf[128 * 64];
  __shared__ __align__(16) ushort Bsf[128 * 64];
  const int tid = threadIdx.x;
  const int bid = blockIdx.x;
  const int work = (bid & 7) * 1024 + (bid >> 3);
  const int mt = work >> 5;
  const int c  = work & 31;
  const int l = (c >= 1) + (c >= 2) + (c >= 5) + (c >= 8) + (c >= 13) + (c >= 18) + (c >= 25);
  const int pp = l >> 1, qq = l & 1;
  const int nirr = l | 1;
  const int cstart = 2 * pp * pp + qq * nirr;
  const int w  = nirr << 7;
  const int sK = cstart << 7;
  const int noff = (c - cstart) << 7;
  const float* __restrict__ Wl = args.W[l];
  const int srow = tid >> 3;
  const int sk   = (tid & 7) << 3;
  const float* ap = args.x + (size_t)(mt * 128 + srow) * TOTALW + sK + sk;
  const float* bp = Wl + (size_t)(noff + srow) * w + sk;
  const size_t aStep = (size_t)32 * TOTALW;
  const size_t bStep = (size_t)32 * w;
  const int lane = tid & 63;
  const int wid  = tid >> 6;
  const int wr = (wid >> 1) << 6;
  const int wc = (wid & 1) << 6;
  const int fr = lane & 15;
  const int kq = lane >> 4;
  f32x4v acc[4][4] = {};
  f32x4 av[4][2], bv[4][2];
  const int nk = w >> 6;
  {
    const float* a = ap; const float* b = bp;
#pragma unroll
    for (int i = 0; i < 4; ++i) {
      av[i][0] = *(const f32x4*)(a); av[i][1] = *(const f32x4*)(a + 4); a += aStep;
      bv[i][0] = *(const f32x4*)(b); bv[i][1] = *(const f32x4*)(b + 4); b += bStep;
    }
  }
  for (int kt = 0; kt < nk; ++kt) {
#pragma unroll
    for (int i = 0; i < 4; ++i) {
      const int row = srow + 32 * i;
      const int e = (row * 64 + sk) ^ ((row & 7) << 3);
      *(bf16x8*)&Asf[e] = cvt8(av[i][0], av[i][1]);
      *(bf16x8*)&Bsf[e] = cvt8(bv[i][0], bv[i][1]);
    }
    __syncthreads();
    if (kt + 1 < nk) {
      const float* a = ap + (kt + 1) * 64;
      const float* b = bp + (kt + 1) * 64;
#pragma unroll
      for (int i = 0; i < 4; ++i) {
        av[i][0] = *(const f32x4*)(a); av[i][1] = *(const f32x4*)(a + 4); a += aStep;
        bv[i][0] = *(const f32x4*)(b); bv[i][1] = *(const f32x4*)(b + 4); b += bStep;
      }
    }
#pragma unroll
    for (int kk = 0; kk < 2; ++kk) {
      const int kb = kk * 32 + kq * 8;
      bf16x8 afr[4], bfr[4];
#pragma unroll
      for (int i = 0; i < 4; ++i) {
        const int ra = wr + i * 16 + fr;
        afr[i] = *(const bf16x8*)&Asf[(ra * 64 + kb) ^ ((fr & 7) << 3)];
        const int rb = wc + i * 16 + fr;
        bfr[i] = *(const bf16x8*)&Bsf[(rb * 64 + kb) ^ ((fr & 7) << 3)];
      }
#pragma unroll
      for (int mi = 0; mi < 4; ++mi)
#pragma unroll
        for (int ni = 0; ni < 4; ++ni)
          acc[mi][ni] = __builtin_amdgcn_mfma_f32_16x16x32_bf16(afr[mi], bfr[ni], acc[mi][ni], 0, 0, 0);
    }
    __syncthreads();
  }
  float* op = args.out + (size_t)(mt * 128 + wr + kq * 4) * TOTALW + (c << 7) + wc + fr;
#pragma unroll
  for (int mi = 0; mi < 4; ++mi) {
#pragma unroll
    for (int ni = 0; ni < 4; ++ni) {
      float* pq = op + (size_t)(mi * 16) * TOTALW + ni * 16;
      pq[0 * TOTALW] = acc[mi][ni][0];
      pq[1 * TOTALW] = acc[mi][ni][1];
      pq[2 * TOTALW] = acc[mi][ni][2];
      pq[3 * TOTALW] = acc[mi][ni][3];
    }
  }
}

extern "C" void kernel_launch(void* const* d_in, const int* in_sizes, int n_in,
                              void* d_out, int out_size, void* d_ws, size_t ws_size,
                              hipStream_t stream) {
  if (ws_size >= WTOT * 2) {
    WCArgs wa;
    for (int i = 0; i < 8; ++i) wa.W[i] = (const float*)d_in[1 + i];
    wa.ws = (ushort*)d_ws;
    wconvert_kernel<<<1344, 256, 0, stream>>>(wa);   // 1344*256*8 == WTOT

    GArgs ga;
    ga.x = (const float*)d_in[0];
    static const size_t cumW[8] = {0, 16384, 32768, 180224, 327680, 737280, 1146880, 1949696};
    for (int i = 0; i < 8; ++i) ga.Wb[i] = (const ushort*)d_ws + cumW[i];
    ga.out = (float*)d_out;
    gemm_kernel<<<5120, 512, 0, stream>>>(ga);
  } else {
    FArgs fa;
    fa.x = (const float*)d_in[0];
    for (int i = 0; i < 8; ++i) fa.W[i] = (const float*)d_in[1 + i];
    fa.out = (float*)d_out;
    ielin_fb<<<8192, 256, 0, stream>>>(fa);
  }
}